// Round 1
// baseline (235.857 us; speedup 1.0000x reference)
//
#include <hip/hip_runtime.h>
#include <hip/hip_bf16.h>

#define M_DIM 2048   // size
#define K_DIM 2048   // prev_size
#define N_DIM 8192   // batch

typedef __attribute__((ext_vector_type(4))) float f32x4;
typedef __attribute__((ext_vector_type(8))) short s16x8;

static __device__ __forceinline__ ushort f2bf(float x) {
    __hip_bfloat16 h = __float2bfloat16(x);
    return *reinterpret_cast<ushort*>(&h);
}

// ---------------- softmax over rows of Wa/Wb -> bf16 probabilities ----------
__global__ __launch_bounds__(256) void softmax_rows_kernel(
    const float* __restrict__ Wa, const float* __restrict__ Wb,
    ushort* __restrict__ Pa, ushort* __restrict__ Pb)
{
    const float* W = blockIdx.y ? Wb : Wa;
    ushort* P = blockIdx.y ? Pb : Pa;
    const int row = blockIdx.x;
    const int t = threadIdx.x;
    const float* w = W + (size_t)row * K_DIM + t * 8;
    float4 v0 = *(const float4*)(w);
    float4 v1 = *(const float4*)(w + 4);
    float x[8] = {v0.x, v0.y, v0.z, v0.w, v1.x, v1.y, v1.z, v1.w};

    float m = x[0];
#pragma unroll
    for (int i = 1; i < 8; ++i) m = fmaxf(m, x[i]);
#pragma unroll
    for (int off = 32; off >= 1; off >>= 1) m = fmaxf(m, __shfl_xor(m, off));
    __shared__ float redm[4], reds[4];
    const int wid = t >> 6;
    if ((t & 63) == 0) redm[wid] = m;
    __syncthreads();
    m = fmaxf(fmaxf(redm[0], redm[1]), fmaxf(redm[2], redm[3]));

    float s = 0.f;
#pragma unroll
    for (int i = 0; i < 8; ++i) { x[i] = __expf(x[i] - m); s += x[i]; }
#pragma unroll
    for (int off = 32; off >= 1; off >>= 1) s += __shfl_xor(s, off);
    if ((t & 63) == 0) reds[wid] = s;
    __syncthreads();
    s = reds[0] + reds[1] + reds[2] + reds[3];
    const float inv = 1.0f / s;

    union { ushort u[8]; int4 v; } pk;
#pragma unroll
    for (int i = 0; i < 8; ++i) pk.u[i] = f2bf(x[i] * inv);
    *(int4*)(P + (size_t)row * K_DIM + t * 8) = pk.v;
}

// ---------- table softmax (over 16) contracted with gate coeffs -> c[4][M] --
__global__ __launch_bounds__(256) void table_c_kernel(
    const float* __restrict__ TW, float4* __restrict__ C4)
{
    const int s = blockIdx.x * 256 + threadIdx.x;
    if (s >= M_DIM) return;
    float x[16];
    float m = -1e30f;
#pragma unroll
    for (int t = 0; t < 16; ++t) { x[t] = TW[t * M_DIM + s]; m = fmaxf(m, x[t]); }
    float sum = 0.f;
#pragma unroll
    for (int t = 0; t < 16; ++t) { x[t] = __expf(x[t] - m); sum += x[t]; }
    const float inv = 1.0f / sum;

    const float c0a[16] = {0,0,0,0,0,0,0,0, 1,1,1,1,1,1,1,1};
    const float cAa[16] = {0,0,1,1,0,0,1,1, -1,-1,0,0,-1,-1,0,0};
    const float cBa[16] = {0,0,0,0,1,1,1,1, -1,-1,-1,-1,0,0,0,0};
    const float cXa[16] = {0,1,-1,0,-1,0,-2,-1, 1,2,0,1,0,1,-1,0};
    float c0 = 0.f, cA = 0.f, cB = 0.f, cX = 0.f;
#pragma unroll
    for (int t = 0; t < 16; ++t) {
        const float p = x[t] * inv;
        c0 += p * c0a[t]; cA += p * cAa[t]; cB += p * cBa[t]; cX += p * cXa[t];
    }
    C4[s] = make_float4(c0, cA, cB, cX);
}

// ---------- prev [K][N] f32 -> prevT [N][K] bf16 (transpose + convert) ------
__global__ __launch_bounds__(256) void transp_conv_kernel(
    const float* __restrict__ src, ushort* __restrict__ dst)
{
    __shared__ ushort tile[64][72];
    const int n0 = blockIdx.x * 64;
    const int k0 = blockIdx.y * 64;
    const int t = threadIdx.x;
#pragma unroll
    for (int it = 0; it < 4; ++it) {
        const int lin = it * 256 + t;      // 0..1023
        const int k = lin >> 4;            // 0..63
        const int n4 = (lin & 15) * 4;     // 0..60
        float4 v = *(const float4*)(src + (size_t)(k0 + k) * N_DIM + n0 + n4);
        tile[n4 + 0][k] = f2bf(v.x);
        tile[n4 + 1][k] = f2bf(v.y);
        tile[n4 + 2][k] = f2bf(v.z);
        tile[n4 + 3][k] = f2bf(v.w);
    }
    __syncthreads();
#pragma unroll
    for (int it = 0; it < 2; ++it) {
        const int lin = it * 256 + t;      // 0..511
        const int n = lin >> 3;            // 0..63
        const int k8 = (lin & 7) * 8;      // 0..56
        int4 v = *(const int4*)&tile[n][k8];
        *(int4*)(dst + (size_t)(n0 + n) * K_DIM + k0 + k8) = v;
    }
}

// ---------------- dual GEMM + gate epilogue ---------------------------------
#define BM 128
#define BN 128
#define BK 64
#define LDSS 72   // padded leading dim (bf16 elems)

__global__ __launch_bounds__(256) void logic_gemm_kernel(
    const ushort* __restrict__ Pa,   // [M][K] bf16
    const ushort* __restrict__ Pb,   // [M][K] bf16
    const ushort* __restrict__ Pt,   // prevT [N][K] bf16
    const float4* __restrict__ C4,   // [M]
    float* __restrict__ out)         // [M][N]
{
    __shared__ ushort sA[BM][LDSS];
    __shared__ ushort sB[BM][LDSS];
    __shared__ ushort sP[BN][LDSS];

    const int m0 = blockIdx.y * BM;
    const int n0 = blockIdx.x * BN;
    const int t = threadIdx.x;
    const int wid = t >> 6, lane = t & 63;
    const int wr = wid >> 1, wc = wid & 1;   // 2x2 waves, each 64x64 out
    const int lq = lane >> 4;                // quad 0..3
    const int lr = lane & 15;

    f32x4 accA[4][4] = {};
    f32x4 accB[4][4] = {};

    for (int k0 = 0; k0 < K_DIM; k0 += BK) {
        __syncthreads();
#pragma unroll
        for (int it = 0; it < 4; ++it) {
            const int lin = it * 256 + t;     // 0..1023
            const int row = lin >> 3;         // 0..127
            const int kc = (lin & 7) * 8;     // 0..56
            int4 va = *(const int4*)(Pa + (size_t)(m0 + row) * K_DIM + k0 + kc);
            int4 vb = *(const int4*)(Pb + (size_t)(m0 + row) * K_DIM + k0 + kc);
            int4 vp = *(const int4*)(Pt + (size_t)(n0 + row) * K_DIM + k0 + kc);
            *(int4*)&sA[row][kc] = va;
            *(int4*)&sB[row][kc] = vb;
            *(int4*)&sP[row][kc] = vp;
        }
        __syncthreads();
#pragma unroll
        for (int kh = 0; kh < 2; ++kh) {
            const int kbase = kh * 32 + lq * 8;
            s16x8 fa[4], fb[4], fp[4];
#pragma unroll
            for (int i = 0; i < 4; ++i) {
                fa[i] = *(const s16x8*)&sA[wr * 64 + i * 16 + lr][kbase];
                fb[i] = *(const s16x8*)&sB[wr * 64 + i * 16 + lr][kbase];
                fp[i] = *(const s16x8*)&sP[wc * 64 + i * 16 + lr][kbase];
            }
#pragma unroll
            for (int mi = 0; mi < 4; ++mi)
#pragma unroll
                for (int ni = 0; ni < 4; ++ni) {
                    accA[mi][ni] = __builtin_amdgcn_mfma_f32_16x16x32_bf16(
                        fa[mi], fp[ni], accA[mi][ni], 0, 0, 0);
                    accB[mi][ni] = __builtin_amdgcn_mfma_f32_16x16x32_bf16(
                        fb[mi], fp[ni], accB[mi][ni], 0, 0, 0);
                }
        }
    }

    // epilogue: out = c0 + cA*A + cB*B + cAB*A*B
#pragma unroll
    for (int mi = 0; mi < 4; ++mi) {
#pragma unroll
        for (int i = 0; i < 4; ++i) {
            const int row = m0 + wr * 64 + mi * 16 + lq * 4 + i;
            const float4 c = C4[row];
#pragma unroll
            for (int ni = 0; ni < 4; ++ni) {
                const int col = n0 + wc * 64 + ni * 16 + lr;
                const float Av = accA[mi][ni][i];
                const float Bv = accB[mi][ni][i];
                out[(size_t)row * N_DIM + col] = c.x + c.y * Av + c.z * Bv + c.w * Av * Bv;
            }
        }
    }
}

extern "C" void kernel_launch(void* const* d_in, const int* in_sizes, int n_in,
                              void* d_out, int out_size, void* d_ws, size_t ws_size,
                              hipStream_t stream) {
    const float* prev = (const float*)d_in[0];   // [2048][8192]
    const float* Wa   = (const float*)d_in[1];   // [2048][2048]
    const float* Wb   = (const float*)d_in[2];   // [2048][2048]
    const float* TW   = (const float*)d_in[3];   // [16][2048]
    float* out = (float*)d_out;                  // [2048][8192]

    char* ws = (char*)d_ws;
    ushort* Pa = (ushort*)(ws);                          //  8 MiB
    ushort* Pb = (ushort*)(ws + (size_t)(8u << 20));     //  8 MiB
    ushort* Pt = (ushort*)(ws + (size_t)(16u << 20));    // 32 MiB
    float4* C4 = (float4*)(ws + (size_t)(48u << 20));    // 32 KiB

    softmax_rows_kernel<<<dim3(2048, 2), 256, 0, stream>>>(Wa, Wb, Pa, Pb);
    table_c_kernel<<<dim3(8), 256, 0, stream>>>(TW, C4);
    transp_conv_kernel<<<dim3(N_DIM / 64, K_DIM / 64), 256, 0, stream>>>(prev, Pt);
    logic_gemm_kernel<<<dim3(N_DIM / BN, M_DIM / BM), 256, 0, stream>>>(Pa, Pb, Pt, C4, out);
}